// Round 5
// baseline (129.677 us; speedup 1.0000x reference)
//
#include <hip/hip_runtime.h>
#include <cstddef>

#define NB 8
#define TQ 2048
#define TV 2048
#define DD 128
#define KVT 32
#define NWV 4           // waves per block (fixed: 256-thread blocks proven good)

typedef _Float16 f16x8 __attribute__((ext_vector_type(8)));
typedef _Float16 f16x4 __attribute__((ext_vector_type(4)));
typedef float f32x4 __attribute__((ext_vector_type(4)));

// ------- prepass: qh = scale * f16(q); kh = f16(k); vt = f16(v)^T [B][D][TV] ---
__global__ __launch_bounds__(256) void prepass_kernel(
    const float* __restrict__ q, const float* __restrict__ k,
    const float* __restrict__ v, const float* __restrict__ scale_p,
    _Float16* __restrict__ qh, _Float16* __restrict__ kh, _Float16* __restrict__ vt)
{
  __shared__ _Float16 tlds[32 * 34];
  const int tid = threadIdx.x;
  const int bid = blockIdx.x;
  if (bid < 2048) {                       // cast+scale Q
    const float sc = scale_p[0];
    size_t idx = (size_t)bid * 256 + tid;
    float4 x = ((const float4*)q)[idx];
    f16x4 h; h[0] = (_Float16)(sc * x.x); h[1] = (_Float16)(sc * x.y);
    h[2] = (_Float16)(sc * x.z); h[3] = (_Float16)(sc * x.w);
    ((f16x4*)qh)[idx] = h;
  } else if (bid < 4096) {                // cast K
    size_t idx = (size_t)(bid - 2048) * 256 + tid;
    float4 x = ((const float4*)k)[idx];
    f16x4 h; h[0] = (_Float16)x.x; h[1] = (_Float16)x.y; h[2] = (_Float16)x.z; h[3] = (_Float16)x.w;
    ((f16x4*)kh)[idx] = h;
  } else {                                // transpose V tile 32x32
    int tb = bid - 4096;                  // 8 b * 64 kt * 4 dt
    int b = tb >> 8, rem = tb & 255;
    int kt = rem >> 2, dt = rem & 3;
    int r = tid >> 3, c0 = (tid & 7) * 4;
    float4 x = *(const float4*)&v[((size_t)b * TV + kt * 32 + r) * DD + dt * 32 + c0];
    tlds[(c0 + 0) * 34 + r] = (_Float16)x.x;
    tlds[(c0 + 1) * 34 + r] = (_Float16)x.y;
    tlds[(c0 + 2) * 34 + r] = (_Float16)x.z;
    tlds[(c0 + 3) * 34 + r] = (_Float16)x.w;
    __syncthreads();
    int dl = tid >> 3, k0 = (tid & 7) * 4;
    f16x4 h;
#pragma unroll
    for (int i = 0; i < 4; ++i) h[i] = tlds[dl * 34 + k0 + i];
    size_t eidx = ((size_t)b * DD + dt * 32 + dl) * TV + kt * 32 + k0;
    *(f16x4*)&vt[eidx] = h;
  }
}

// ------- main: 256-thread blocks, 4 waves, 32 Q rows/block, KV split -----------
// SPLIT=1: grid 512,   each block all 2048 KV (wave chunk 512), writes out.
// SPLIT=2: grid 1024,  each block half   KV (wave chunk 256), writes partials.
template <int SPLIT>
__global__ __launch_bounds__(256, 4) void attn_part(
    const _Float16* __restrict__ qh, const _Float16* __restrict__ kh,
    const _Float16* __restrict__ vt,
    const int* __restrict__ mask_q, const int* __restrict__ mask_v,
    float* __restrict__ out,
    float* __restrict__ pO, float* __restrict__ pm, float* __restrict__ pl)
{
  __shared__ __align__(16) _Float16 plds_all[NWV][2][16 * 40];
  __shared__ __align__(16) float osh[32 * 132];
  __shared__ float msh[NWV][32], lsh[NWV][32];

  const int tid = threadIdx.x;
  const int w = tid >> 6;
  const int lane = tid & 63;
  const int l15 = lane & 15, lg = lane >> 4;

  const int b = blockIdx.x & 7;            // batch -> XCD affinity (256-thr proven)
  const int qg = (blockIdx.x >> 3) & 63;   // 0..63
  const int half = blockIdx.x >> 9;        // 0 for SPLIT=1
  const int qbase = qg * 32;
  const int CHW = TV / (NWV * SPLIT);      // KV rows per wave
  const int kv0 = half * (TV / SPLIT) + w * CHW;

  const _Float16* qhb = qh + ((size_t)b * TQ + qbase) * DD;
  const _Float16* khb = kh + (size_t)b * TV * DD;
  const _Float16* vtb = vt + (size_t)b * DD * TV;
  const int* mvb = mask_v + b * TV;

  f16x8 qf[2][4];
#pragma unroll
  for (int rb = 0; rb < 2; ++rb)
#pragma unroll
    for (int kc = 0; kc < 4; ++kc)
      qf[rb][kc] = *(const f16x8*)(qhb + (size_t)(rb * 16 + l15) * DD + kc * 32 + lg * 8);

  f32x4 acc[2][8];
#pragma unroll
  for (int rb = 0; rb < 2; ++rb)
#pragma unroll
    for (int ct = 0; ct < 8; ++ct) acc[rb][ct] = (f32x4){0.f, 0.f, 0.f, 0.f};
  float m[2][4], lsum[2][4];
#pragma unroll
  for (int rb = 0; rb < 2; ++rb)
#pragma unroll
    for (int r = 0; r < 4; ++r) { m[rb][r] = -3.0e38f; lsum[rb][r] = 0.f; }

  for (int t = 0; t < CHW / KVT; ++t) {
    const int kt = kv0 + t * KVT;
    f32x4 s[2][2];
    s[0][0] = (f32x4){0,0,0,0}; s[0][1] = (f32x4){0,0,0,0};
    s[1][0] = (f32x4){0,0,0,0}; s[1][1] = (f32x4){0,0,0,0};
#pragma unroll
    for (int kc = 0; kc < 4; ++kc) {
      f16x8 kf0 = *(const f16x8*)(khb + (size_t)(kt + l15) * DD + kc * 32 + lg * 8);
      f16x8 kf1 = *(const f16x8*)(khb + (size_t)(kt + 16 + l15) * DD + kc * 32 + lg * 8);
      s[0][0] = __builtin_amdgcn_mfma_f32_16x16x32_f16(qf[0][kc], kf0, s[0][0], 0, 0, 0);
      s[1][0] = __builtin_amdgcn_mfma_f32_16x16x32_f16(qf[1][kc], kf0, s[1][0], 0, 0, 0);
      s[0][1] = __builtin_amdgcn_mfma_f32_16x16x32_f16(qf[0][kc], kf1, s[0][1], 0, 0, 0);
      s[1][1] = __builtin_amdgcn_mfma_f32_16x16x32_f16(qf[1][kc], kf1, s[1][1], 0, 0, 0);
    }
    const float a0 = (mvb[kt + l15]      != 0) ? 0.f : -1e9f;
    const float a1 = (mvb[kt + 16 + l15] != 0) ? 0.f : -1e9f;

    f16x8 pa[2];
#pragma unroll
    for (int rb = 0; rb < 2; ++rb) {
      float pmax[4];
#pragma unroll
      for (int r = 0; r < 4; ++r) {
        s[rb][0][r] += a0;
        s[rb][1][r] += a1;
        pmax[r] = fmaxf(s[rb][0][r], s[rb][1][r]);
      }
#pragma unroll
      for (int off = 1; off < 16; off <<= 1)
#pragma unroll
        for (int r = 0; r < 4; ++r)
          pmax[r] = fmaxf(pmax[r], __shfl_xor(pmax[r], off, 64));

      float al[4], ps[4];
      _Float16* pl2 = plds_all[w][rb];
#pragma unroll
      for (int r = 0; r < 4; ++r) {
        float mn = fmaxf(m[rb][r], pmax[r]);
        al[r] = __expf(m[rb][r] - mn);
        m[rb][r] = mn;
        float p0 = __expf(s[rb][0][r] - mn);
        float p1 = __expf(s[rb][1][r] - mn);
        ps[r] = p0 + p1;
        int row = lg * 4 + r;
        pl2[row * 40 + l15]      = (_Float16)p0;
        pl2[row * 40 + 16 + l15] = (_Float16)p1;
      }
#pragma unroll
      for (int off = 1; off < 16; off <<= 1)
#pragma unroll
        for (int r = 0; r < 4; ++r)
          ps[r] += __shfl_xor(ps[r], off, 64);
      f32x4 alv;
#pragma unroll
      for (int r = 0; r < 4; ++r) {
        lsum[rb][r] = lsum[rb][r] * al[r] + ps[r];
        alv[r] = al[r];
      }
#pragma unroll
      for (int ct = 0; ct < 8; ++ct) acc[rb][ct] *= alv;
      pa[rb] = *(const f16x8*)(pl2 + l15 * 40 + lg * 8);
    }

#pragma unroll
    for (int ct = 0; ct < 8; ++ct) {
      f16x8 vf = *(const f16x8*)(vtb + (size_t)(ct * 16 + l15) * TV + kt + lg * 8);
      acc[0][ct] = __builtin_amdgcn_mfma_f32_16x16x32_f16(pa[0], vf, acc[0][ct], 0, 0, 0);
      acc[1][ct] = __builtin_amdgcn_mfma_f32_16x16x32_f16(pa[1], vf, acc[1][ct], 0, 0, 0);
    }
  }

  // ---- publish per-wave stats ----
  if (l15 == 0) {
#pragma unroll
    for (int rb = 0; rb < 2; ++rb)
#pragma unroll
      for (int r = 0; r < 4; ++r) {
        msh[w][rb * 16 + lg * 4 + r] = m[rb][r];
        lsh[w][rb * 16 + lg * 4 + r] = lsum[rb][r];
      }
  }
  __syncthreads();

  // per-wave rescale coefficient to the block max
  float coef[2][4];
#pragma unroll
  for (int rb = 0; rb < 2; ++rb)
#pragma unroll
    for (int r = 0; r < 4; ++r) {
      int row = rb * 16 + lg * 4 + r;
      float mstar = msh[0][row];
#pragma unroll
      for (int wv = 1; wv < NWV; ++wv) mstar = fmaxf(mstar, msh[wv][row]);
      coef[rb][r] = __expf(m[rb][r] - mstar);
    }

  // sequential accumulate into osh (NWV barriers, epilogue-only)
#pragma unroll
  for (int wv = 0; wv < NWV; ++wv) {
    if (w == wv) {
#pragma unroll
      for (int rb = 0; rb < 2; ++rb)
#pragma unroll
        for (int ct = 0; ct < 8; ++ct)
#pragma unroll
          for (int r = 0; r < 4; ++r) {
            int idx = (rb * 16 + lg * 4 + r) * 132 + ct * 16 + l15;
            float val = coef[rb][r] * acc[rb][ct][r];
            if (wv == 0) osh[idx] = val; else osh[idx] += val;
          }
    }
    __syncthreads();
  }

  if (SPLIT == 1) {
    // ---- final normalize + query-mask + store ----
    const int row = tid >> 3;            // 0..31
    const int cg = (tid & 7) * 16;       // 0..112
    float mstar = msh[0][row];
#pragma unroll
    for (int wv = 1; wv < NWV; ++wv) mstar = fmaxf(mstar, msh[wv][row]);
    float lstar = 0.f;
#pragma unroll
    for (int wv = 0; wv < NWV; ++wv)
      lstar += __expf(msh[wv][row] - mstar) * lsh[wv][row];
    const int qr = qbase + row;
    const float f = ((mask_q[(size_t)b * TQ + qr] != 0) ? 1.f : 0.f) / lstar;
    float* orow = out + ((size_t)b * TQ + qr) * DD + cg;
#pragma unroll
    for (int i4 = 0; i4 < 4; ++i4) {
      float4 p = *(float4*)&osh[row * 132 + cg + i4 * 4];
      float4 o; o.x = p.x * f; o.y = p.y * f; o.z = p.z * f; o.w = p.w * f;
      *(float4*)(orow + i4 * 4) = o;
    }
  } else {
    // ---- write partials (unnormalized O at block max, plus m*, l*) ----
    const int prt = ((b * 64 + qg) * 2 + half);
    float* po = pO + (size_t)prt * 32 * 128;
    const int row = tid >> 3;
    const int cg = (tid & 7) * 16;
#pragma unroll
    for (int i4 = 0; i4 < 4; ++i4)
      *(float4*)&po[row * 128 + cg + i4 * 4] = *(float4*)&osh[row * 132 + cg + i4 * 4];
    if (tid < 32) {
      float mstar = msh[0][tid];
#pragma unroll
      for (int wv = 1; wv < NWV; ++wv) mstar = fmaxf(mstar, msh[wv][tid]);
      float lstar = 0.f;
#pragma unroll
      for (int wv = 0; wv < NWV; ++wv)
        lstar += __expf(msh[wv][tid] - mstar) * lsh[wv][tid];
      pm[prt * 32 + tid] = mstar;
      pl[prt * 32 + tid] = lstar;
    }
  }
}

// ------- combine two KV-half partials per 32-row Q tile ------------------------
__global__ __launch_bounds__(256) void combine_kernel(
    const float* __restrict__ pO, const float* __restrict__ pm,
    const float* __restrict__ pl, const int* __restrict__ mask_q,
    float* __restrict__ out)
{
  const int qt = blockIdx.x;            // 0..511 : qt = b*64 + qg
  const int b = qt >> 6, qg = qt & 63;
  const int row = threadIdx.x >> 3;     // 0..31
  const int cg = (threadIdx.x & 7) * 16;
  const int p0 = qt * 2, p1 = qt * 2 + 1;

  const float m0 = pm[p0 * 32 + row], m1 = pm[p1 * 32 + row];
  const float l0 = pl[p0 * 32 + row], l1 = pl[p1 * 32 + row];
  const float ms = fmaxf(m0, m1);
  const float w0 = __expf(m0 - ms), w1 = __expf(m1 - ms);
  const float l = w0 * l0 + w1 * l1;
  const int qr = qg * 32 + row;
  const float f = ((mask_q[(size_t)b * TQ + qr] != 0) ? 1.f : 0.f) / l;

  const float* o0 = pO + ((size_t)p0 * 32 + row) * 128 + cg;
  const float* o1 = pO + ((size_t)p1 * 32 + row) * 128 + cg;
  float* orow = out + ((size_t)b * TQ + qr) * DD + cg;
#pragma unroll
  for (int i4 = 0; i4 < 4; ++i4) {
    float4 a = *(const float4*)(o0 + i4 * 4);
    float4 c = *(const float4*)(o1 + i4 * 4);
    float4 o;
    o.x = (w0 * a.x + w1 * c.x) * f;
    o.y = (w0 * a.y + w1 * c.y) * f;
    o.z = (w0 * a.z + w1 * c.z) * f;
    o.w = (w0 * a.w + w1 * c.w) * f;
    *(float4*)(orow + i4 * 4) = o;
  }
}

// ---------------- fallback (round-1 kernel) if ws too small --------------------
__global__ __launch_bounds__(64, 4) void attn_f32_kernel(
    const float* __restrict__ q, const float* __restrict__ v,
    const float* __restrict__ k, const float* __restrict__ scale_p,
    const int* __restrict__ mask_q, const int* __restrict__ mask_v,
    float* __restrict__ out)
{
  __shared__ __align__(16) _Float16 plds[16 * 40];
  const int lane = threadIdx.x & 63;
  const int l15 = lane & 15, lg = lane >> 4;
  const int qblocks = TQ / 16;
  const int b = blockIdx.x / qblocks, qb = blockIdx.x % qblocks;
  const int qbase = qb * 16;
  const float scale = scale_p[0];
  const float* qp = q + ((size_t)b * TQ + qbase) * DD;
  const float* kbase = k + (size_t)b * TV * DD;
  const float* vbase = v + (size_t)b * TV * DD;
  const int* mvb = mask_v + b * TV;
  f16x8 qf[4];
#pragma unroll
  for (int kc = 0; kc < 4; ++kc) {
    float4 a = *(const float4*)(qp + (size_t)l15 * DD + kc * 32 + lg * 8);
    float4 bb = *(const float4*)(qp + (size_t)l15 * DD + kc * 32 + lg * 8 + 4);
    f16x8 h; h[0]=(_Float16)a.x;h[1]=(_Float16)a.y;h[2]=(_Float16)a.z;h[3]=(_Float16)a.w;
    h[4]=(_Float16)bb.x;h[5]=(_Float16)bb.y;h[6]=(_Float16)bb.z;h[7]=(_Float16)bb.w;
    qf[kc]=h;
  }
  f32x4 acc[8];
#pragma unroll
  for (int i = 0; i < 8; ++i) acc[i] = (f32x4){0.f,0.f,0.f,0.f};
  float m[4], lsum[4];
#pragma unroll
  for (int r = 0; r < 4; ++r) { m[r] = -3.0e38f; lsum[r] = 0.f; }
  for (int kt = 0; kt < TV; kt += KVT) {
    f32x4 s0 = {0,0,0,0}, s1 = {0,0,0,0};
#pragma unroll
    for (int kc = 0; kc < 4; ++kc) {
      const float* kp0 = kbase + (size_t)(kt + l15) * DD + kc * 32 + lg * 8;
      float4 a = *(const float4*)kp0; float4 bb = *(const float4*)(kp0 + 4);
      f16x8 kf0; kf0[0]=(_Float16)a.x;kf0[1]=(_Float16)a.y;kf0[2]=(_Float16)a.z;kf0[3]=(_Float16)a.w;
      kf0[4]=(_Float16)bb.x;kf0[5]=(_Float16)bb.y;kf0[6]=(_Float16)bb.z;kf0[7]=(_Float16)bb.w;
      s0 = __builtin_amdgcn_mfma_f32_16x16x32_f16(qf[kc], kf0, s0, 0, 0, 0);
      const float* kp1 = kbase + (size_t)(kt + 16 + l15) * DD + kc * 32 + lg * 8;
      a = *(const float4*)kp1; bb = *(const float4*)(kp1 + 4);
      f16x8 kf1; kf1[0]=(_Float16)a.x;kf1[1]=(_Float16)a.y;kf1[2]=(_Float16)a.z;kf1[3]=(_Float16)a.w;
      kf1[4]=(_Float16)bb.x;kf1[5]=(_Float16)bb.y;kf1[6]=(_Float16)bb.z;kf1[7]=(_Float16)bb.w;
      s1 = __builtin_amdgcn_mfma_f32_16x16x32_f16(qf[kc], kf1, s1, 0, 0, 0);
    }
    const float a0 = (mvb[kt + l15] != 0) ? 0.f : -1e9f;
    const float a1 = (mvb[kt + 16 + l15] != 0) ? 0.f : -1e9f;
    float pmx[4];
#pragma unroll
    for (int r = 0; r < 4; ++r) {
      s0[r] = s0[r] * scale + a0; s1[r] = s1[r] * scale + a1;
      pmx[r] = fmaxf(s0[r], s1[r]);
    }
#pragma unroll
    for (int off = 1; off < 16; off <<= 1)
#pragma unroll
      for (int r = 0; r < 4; ++r) pmx[r] = fmaxf(pmx[r], __shfl_xor(pmx[r], off, 64));
    float al[4], ps[4];
#pragma unroll
    for (int r = 0; r < 4; ++r) {
      float mn = fmaxf(m[r], pmx[r]);
      al[r] = __expf(m[r] - mn); m[r] = mn;
      float p0 = __expf(s0[r] - mn), p1 = __expf(s1[r] - mn);
      ps[r] = p0 + p1;
      int row = lg * 4 + r;
      plds[row * 40 + l15] = (_Float16)p0;
      plds[row * 40 + 16 + l15] = (_Float16)p1;
    }
#pragma unroll
    for (int off = 1; off < 16; off <<= 1)
#pragma unroll
      for (int r = 0; r < 4; ++r) ps[r] += __shfl_xor(ps[r], off, 64);
#pragma unroll
    for (int r = 0; r < 4; ++r) {
      lsum[r] = lsum[r] * al[r] + ps[r];
#pragma unroll
      for (int ct = 0; ct < 8; ++ct) acc[ct][r] *= al[r];
    }
    f16x8 pa = *(const f16x8*)&plds[l15 * 40 + lg * 8];
#pragma unroll
    for (int ct = 0; ct < 8; ++ct) {
      const float* vp = vbase + (size_t)(kt + lg * 8) * DD + ct * 16 + l15;
      f16x8 vf;
#pragma unroll
      for (int j = 0; j < 8; ++j) vf[j] = (_Float16)vp[(size_t)j * DD];
      acc[ct] = __builtin_amdgcn_mfma_f32_16x16x32_f16(pa, vf, acc[ct], 0, 0, 0);
    }
  }
  const int* mqb = mask_q + b * TQ;
#pragma unroll
  for (int r = 0; r < 4; ++r) {
    int row = lg * 4 + r;
    int qr = qbase + row;
    float f = ((mqb[qr] != 0) ? 1.f : 0.f) / lsum[r];
    float* orow = out + ((size_t)b * TQ + qr) * DD;
#pragma unroll
    for (int ct = 0; ct < 8; ++ct) orow[ct * 16 + l15] = acc[ct][r] * f;
  }
}

extern "C" void kernel_launch(void* const* d_in, const int* in_sizes, int n_in,
                              void* d_out, int out_size, void* d_ws, size_t ws_size,
                              hipStream_t stream) {
  const float* q      = (const float*)d_in[0];
  const float* v      = (const float*)d_in[1];
  const float* k      = (const float*)d_in[2];
  const float* scale  = (const float*)d_in[3];
  const int*   mask_q = (const int*)d_in[4];
  const int*   mask_v = (const int*)d_in[5];
  float* out = (float*)d_out;

  const size_t need1 = 3ull * NB * TV * DD * sizeof(_Float16);          // 12 MB
  const size_t poBytes = 1024ull * 32 * 128 * sizeof(float);            // 16 MB
  const size_t pmBytes = 1024ull * 32 * sizeof(float);                  // 128 KB
  const size_t need2 = need1 + poBytes + 2 * pmBytes;                   // ~28.3 MB

  if (ws_size >= need1) {
    _Float16* qh = (_Float16*)d_ws;
    _Float16* kh = qh + (size_t)NB * TQ * DD;
    _Float16* vt = kh + (size_t)NB * TV * DD;
    hipLaunchKernelGGL(prepass_kernel, dim3(4096 + 2048), dim3(256), 0, stream,
                       q, k, v, scale, qh, kh, vt);
    if (ws_size >= need2) {
      float* pO = (float*)((char*)d_ws + need1);
      float* pm = pO + 1024ull * 32 * 128;
      float* pl = pm + 1024ull * 32;
      hipLaunchKernelGGL((attn_part<2>), dim3(1024), dim3(256), 0, stream,
                         qh, kh, vt, mask_q, mask_v, out, pO, pm, pl);
      hipLaunchKernelGGL(combine_kernel, dim3(512), dim3(256), 0, stream,
                         pO, pm, pl, mask_q, out);
    } else {
      hipLaunchKernelGGL((attn_part<1>), dim3(512), dim3(256), 0, stream,
                         qh, kh, vt, mask_q, mask_v, out,
                         (float*)nullptr, (float*)nullptr, (float*)nullptr);
    }
  } else {
    hipLaunchKernelGGL(attn_f32_kernel, dim3(NB * (TQ / 16)), dim3(64), 0, stream,
                       q, v, k, scale, mask_q, mask_v, out);
  }
}

// Round 6
// 80.898 us; speedup vs baseline: 1.6030x; 1.6030x over previous
//
#include <hip/hip_runtime.h>
#include <cstddef>

#define NB 8
#define TQ 2048
#define TV 2048
#define DD 128
#define KVT 32
#define NWV 4           // waves per block; chunk = 512 KV rows/wave (PROVEN: FETCH stays ~6 MB)
#define CHW (TV / NWV)  // 512
#define NT  (CHW / KVT) // 16 tiles per wave

typedef _Float16 f16x8 __attribute__((ext_vector_type(8)));
typedef _Float16 f16x4 __attribute__((ext_vector_type(4)));
typedef float f32x4 __attribute__((ext_vector_type(4)));

// DPP row rotate (within 16-lane row) -- VALU-speed cross-lane, no LDS latency
template <int CTRL>
__device__ __forceinline__ float dpp_mov(float x) {
  return __builtin_bit_cast(float,
      __builtin_amdgcn_update_dpp(0, __builtin_bit_cast(int, x), CTRL, 0xF, 0xF, true));
}
__device__ __forceinline__ float rowmax16(float x) {
  x = fmaxf(x, dpp_mov<0x128>(x));  // row_ror:8
  x = fmaxf(x, dpp_mov<0x124>(x));  // row_ror:4
  x = fmaxf(x, dpp_mov<0x122>(x));  // row_ror:2
  x = fmaxf(x, dpp_mov<0x121>(x));  // row_ror:1
  return x;
}

// ------- prepass: qh = scale * f16(q); kh = f16(k); vt = f16(v)^T [B][D][TV] ---
__global__ __launch_bounds__(256) void prepass_kernel(
    const float* __restrict__ q, const float* __restrict__ k,
    const float* __restrict__ v, const float* __restrict__ scale_p,
    _Float16* __restrict__ qh, _Float16* __restrict__ kh, _Float16* __restrict__ vt)
{
  __shared__ _Float16 tlds[32 * 34];
  const int tid = threadIdx.x;
  const int bid = blockIdx.x;
  if (bid < 2048) {                       // cast+scale Q
    const float sc = scale_p[0];
    size_t idx = (size_t)bid * 256 + tid;
    float4 x = ((const float4*)q)[idx];
    f16x4 h; h[0] = (_Float16)(sc * x.x); h[1] = (_Float16)(sc * x.y);
    h[2] = (_Float16)(sc * x.z); h[3] = (_Float16)(sc * x.w);
    ((f16x4*)qh)[idx] = h;
  } else if (bid < 4096) {                // cast K
    size_t idx = (size_t)(bid - 2048) * 256 + tid;
    float4 x = ((const float4*)k)[idx];
    f16x4 h; h[0] = (_Float16)x.x; h[1] = (_Float16)x.y; h[2] = (_Float16)x.z; h[3] = (_Float16)x.w;
    ((f16x4*)kh)[idx] = h;
  } else {                                // transpose V tile 32x32
    int tb = bid - 4096;                  // 8 b * 64 kt * 4 dt
    int b = tb >> 8, rem = tb & 255;
    int kt = rem >> 2, dt = rem & 3;
    int r = tid >> 3, c0 = (tid & 7) * 4;
    float4 x = *(const float4*)&v[((size_t)b * TV + kt * 32 + r) * DD + dt * 32 + c0];
    tlds[(c0 + 0) * 34 + r] = (_Float16)x.x;
    tlds[(c0 + 1) * 34 + r] = (_Float16)x.y;
    tlds[(c0 + 2) * 34 + r] = (_Float16)x.z;
    tlds[(c0 + 3) * 34 + r] = (_Float16)x.w;
    __syncthreads();
    int dl = tid >> 3, k0 = (tid & 7) * 4;
    f16x4 h;
#pragma unroll
    for (int i = 0; i < 4; ++i) h[i] = tlds[dl * 34 + k0 + i];
    size_t eidx = ((size_t)b * DD + dt * 32 + dl) * TV + kt * 32 + k0;
    *(f16x4*)&vt[eidx] = h;
  }
}

// ------- main: grid 512 (b=blk&7), 4 waves x 32 Q rows x 512-KV chunk ----------
__global__ __launch_bounds__(256, 2) void attn_main(
    const _Float16* __restrict__ qh, const _Float16* __restrict__ kh,
    const _Float16* __restrict__ vt,
    const int* __restrict__ mask_q, const int* __restrict__ mask_v,
    float* __restrict__ out)
{
  __shared__ __align__(16) _Float16 plds_all[NWV][2][16 * 40];
  __shared__ __align__(16) float osh[32 * 132];
  __shared__ float msh[NWV][32], lsh[NWV][32];

  const int tid = threadIdx.x;
  const int w = tid >> 6;
  const int lane = tid & 63;
  const int l15 = lane & 15, lg = lane >> 4;

  const int b = blockIdx.x & 7;            // batch -> XCD affinity (r2-proven mapping)
  const int qg = blockIdx.x >> 3;          // 0..63
  const int qbase = qg * 32;
  const int kv0 = w * CHW;

  const _Float16* qhb = qh + ((size_t)b * TQ + qbase) * DD;
  const _Float16* khb = kh + (size_t)b * TV * DD;
  const _Float16* vtb = vt + (size_t)b * DD * TV;
  const int* mvb = mask_v + b * TV;

  f16x8 qf[2][4];
#pragma unroll
  for (int rb = 0; rb < 2; ++rb)
#pragma unroll
    for (int kc = 0; kc < 4; ++kc)
      qf[rb][kc] = *(const f16x8*)(qhb + (size_t)(rb * 16 + l15) * DD + kc * 32 + lg * 8);

  f16x8 vones;
#pragma unroll
  for (int j = 0; j < 8; ++j) vones[j] = (_Float16)1.f;

  f32x4 acc[2][8];
  f32x4 accl[2];
#pragma unroll
  for (int rb = 0; rb < 2; ++rb) {
    accl[rb] = (f32x4){0.f, 0.f, 0.f, 0.f};
#pragma unroll
    for (int ct = 0; ct < 8; ++ct) acc[rb][ct] = (f32x4){0.f, 0.f, 0.f, 0.f};
  }
  float m[2][4];
#pragma unroll
  for (int rb = 0; rb < 2; ++rb)
#pragma unroll
    for (int r = 0; r < 4; ++r) m[rb][r] = -3.0e38f;

  for (int t = 0; t < NT; ++t) {
    const int kt = kv0 + t * KVT;

    // ---- QK^T ----
    f32x4 s[2][2];
    s[0][0] = (f32x4){0,0,0,0}; s[0][1] = (f32x4){0,0,0,0};
    s[1][0] = (f32x4){0,0,0,0}; s[1][1] = (f32x4){0,0,0,0};
    __builtin_amdgcn_s_setprio(1);
#pragma unroll
    for (int kc = 0; kc < 4; ++kc) {
      f16x8 kf0 = *(const f16x8*)(khb + (size_t)(kt + l15) * DD + kc * 32 + lg * 8);
      f16x8 kf1 = *(const f16x8*)(khb + (size_t)(kt + 16 + l15) * DD + kc * 32 + lg * 8);
      s[0][0] = __builtin_amdgcn_mfma_f32_16x16x32_f16(qf[0][kc], kf0, s[0][0], 0, 0, 0);
      s[1][0] = __builtin_amdgcn_mfma_f32_16x16x32_f16(qf[1][kc], kf0, s[1][0], 0, 0, 0);
      s[0][1] = __builtin_amdgcn_mfma_f32_16x16x32_f16(qf[0][kc], kf1, s[0][1], 0, 0, 0);
      s[1][1] = __builtin_amdgcn_mfma_f32_16x16x32_f16(qf[1][kc], kf1, s[1][1], 0, 0, 0);
    }
    __builtin_amdgcn_s_setprio(0);

    // ---- V loads: independent of softmax, issue NOW so L2 latency hides ----
    f16x8 vf[8];
#pragma unroll
    for (int ct = 0; ct < 8; ++ct)
      vf[ct] = *(const f16x8*)(vtb + (size_t)(ct * 16 + l15) * TV + kt + lg * 8);

    const float a0 = (mvb[kt + l15]      != 0) ? 0.f : -1e9f;
    const float a1 = (mvb[kt + 16 + l15] != 0) ? 0.f : -1e9f;

    // ---- softmax (DPP row-max, defer-max, exp, LDS P-transpose) ----
    f16x8 pa[2];
#pragma unroll
    for (int rb = 0; rb < 2; ++rb) {
      float pmx[4];
      bool grow = false;
#pragma unroll
      for (int r = 0; r < 4; ++r) {
        s[rb][0][r] += a0;
        s[rb][1][r] += a1;
        pmx[r] = rowmax16(fmaxf(s[rb][0][r], s[rb][1][r]));
        grow = grow || (pmx[r] > m[rb][r] + 8.f);
      }
      if (__any(grow)) {                 // wave-uniform rescale (rare after warmup)
        f32x4 alv;
#pragma unroll
        for (int r = 0; r < 4; ++r) {
          float mn = fmaxf(m[rb][r], pmx[r]);
          alv[r] = __expf(m[rb][r] - mn);
          m[rb][r] = mn;
        }
        accl[rb] *= alv;
#pragma unroll
        for (int ct = 0; ct < 8; ++ct) acc[rb][ct] *= alv;
      }
      _Float16* pl = plds_all[w][rb];
#pragma unroll
      for (int r = 0; r < 4; ++r) {
        float p0 = __expf(s[rb][0][r] - m[rb][r]);
        float p1 = __expf(s[rb][1][r] - m[rb][r]);
        int row = lg * 4 + r;
        pl[row * 40 + l15]      = (_Float16)p0;
        pl[row * 40 + 16 + l15] = (_Float16)p1;
      }
      pa[rb] = *(const f16x8*)(pl + l15 * 40 + lg * 8);
    }

    // ---- PV (+ ones-column MFMA computes row-sums into accl) ----
    __builtin_amdgcn_s_setprio(1);
#pragma unroll
    for (int ct = 0; ct < 8; ++ct) {
      acc[0][ct] = __builtin_amdgcn_mfma_f32_16x16x32_f16(pa[0], vf[ct], acc[0][ct], 0, 0, 0);
      acc[1][ct] = __builtin_amdgcn_mfma_f32_16x16x32_f16(pa[1], vf[ct], acc[1][ct], 0, 0, 0);
    }
    accl[0] = __builtin_amdgcn_mfma_f32_16x16x32_f16(pa[0], vones, accl[0], 0, 0, 0);
    accl[1] = __builtin_amdgcn_mfma_f32_16x16x32_f16(pa[1], vones, accl[1], 0, 0, 0);
    __builtin_amdgcn_s_setprio(0);
  }

  // ---- publish per-wave stats ----
  if (l15 == 0) {
#pragma unroll
    for (int rb = 0; rb < 2; ++rb)
#pragma unroll
      for (int r = 0; r < 4; ++r) {
        msh[w][rb * 16 + lg * 4 + r] = m[rb][r];
        lsh[w][rb * 16 + lg * 4 + r] = accl[rb][r];
      }
  }
  __syncthreads();

  // per-wave rescale coefficient to the block max
  float coef[2][4];
#pragma unroll
  for (int rb = 0; rb < 2; ++rb)
#pragma unroll
    for (int r = 0; r < 4; ++r) {
      int row = rb * 16 + lg * 4 + r;
      float mstar = msh[0][row];
#pragma unroll
      for (int wv = 1; wv < NWV; ++wv) mstar = fmaxf(mstar, msh[wv][row]);
      coef[rb][r] = __expf(m[rb][r] - mstar);
    }

  // sequential accumulate into osh (NWV barriers, epilogue-only)
#pragma unroll
  for (int wv = 0; wv < NWV; ++wv) {
    if (w == wv) {
#pragma unroll
      for (int rb = 0; rb < 2; ++rb)
#pragma unroll
        for (int ct = 0; ct < 8; ++ct)
#pragma unroll
          for (int r = 0; r < 4; ++r) {
            int idx = (rb * 16 + lg * 4 + r) * 132 + ct * 16 + l15;
            float val = coef[rb][r] * acc[rb][ct][r];
            if (wv == 0) osh[idx] = val; else osh[idx] += val;
          }
    }
    __syncthreads();
  }

  // ---- final normalize + query-mask + store ----
  {
    const int row = tid >> 3;            // 0..31
    const int cg = (tid & 7) * 16;       // 0..112
    float mstar = msh[0][row];
#pragma unroll
    for (int wv = 1; wv < NWV; ++wv) mstar = fmaxf(mstar, msh[wv][row]);
    float lstar = 0.f;
#pragma unroll
    for (int wv = 0; wv < NWV; ++wv)
      lstar += __expf(msh[wv][row] - mstar) * lsh[wv][row];
    const int qr = qbase + row;
    const float f = ((mask_q[(size_t)b * TQ + qr] != 0) ? 1.f : 0.f) / lstar;
    float* orow = out + ((size_t)b * TQ + qr) * DD + cg;
#pragma unroll
    for (int i4 = 0; i4 < 4; ++i4) {
      float4 p = *(float4*)&osh[row * 132 + cg + i4 * 4];
      float4 o; o.x = p.x * f; o.y = p.y * f; o.z = p.z * f; o.w = p.w * f;
      *(float4*)(orow + i4 * 4) = o;
    }
  }
}

// ---------------- fallback (round-1 kernel) if ws too small --------------------
__global__ __launch_bounds__(64, 4) void attn_f32_kernel(
    const float* __restrict__ q, const float* __restrict__ v,
    const float* __restrict__ k, const float* __restrict__ scale_p,
    const int* __restrict__ mask_q, const int* __restrict__ mask_v,
    float* __restrict__ out)
{
  __shared__ __align__(16) _Float16 plds[16 * 40];
  const int lane = threadIdx.x & 63;
  const int l15 = lane & 15, lg = lane >> 4;
  const int qblocks = TQ / 16;
  const int b = blockIdx.x / qblocks, qb = blockIdx.x % qblocks;
  const int qbase = qb * 16;
  const float scale = scale_p[0];
  const float* qp = q + ((size_t)b * TQ + qbase) * DD;
  const float* kbase = k + (size_t)b * TV * DD;
  const float* vbase = v + (size_t)b * TV * DD;
  const int* mvb = mask_v + b * TV;
  f16x8 qf[4];
#pragma unroll
  for (int kc = 0; kc < 4; ++kc) {
    float4 a = *(const float4*)(qp + (size_t)l15 * DD + kc * 32 + lg * 8);
    float4 bb = *(const float4*)(qp + (size_t)l15 * DD + kc * 32 + lg * 8 + 4);
    f16x8 h; h[0]=(_Float16)a.x;h[1]=(_Float16)a.y;h[2]=(_Float16)a.z;h[3]=(_Float16)a.w;
    h[4]=(_Float16)bb.x;h[5]=(_Float16)bb.y;h[6]=(_Float16)bb.z;h[7]=(_Float16)bb.w;
    qf[kc]=h;
  }
  f32x4 acc[8];
#pragma unroll
  for (int i = 0; i < 8; ++i) acc[i] = (f32x4){0.f,0.f,0.f,0.f};
  float m[4], lsum[4];
#pragma unroll
  for (int r = 0; r < 4; ++r) { m[r] = -3.0e38f; lsum[r] = 0.f; }
  for (int kt = 0; kt < TV; kt += KVT) {
    f32x4 s0 = {0,0,0,0}, s1 = {0,0,0,0};
#pragma unroll
    for (int kc = 0; kc < 4; ++kc) {
      const float* kp0 = kbase + (size_t)(kt + l15) * DD + kc * 32 + lg * 8;
      float4 a = *(const float4*)kp0; float4 bb = *(const float4*)(kp0 + 4);
      f16x8 kf0; kf0[0]=(_Float16)a.x;kf0[1]=(_Float16)a.y;kf0[2]=(_Float16)a.z;kf0[3]=(_Float16)a.w;
      kf0[4]=(_Float16)bb.x;kf0[5]=(_Float16)bb.y;kf0[6]=(_Float16)bb.z;kf0[7]=(_Float16)bb.w;
      s0 = __builtin_amdgcn_mfma_f32_16x16x32_f16(qf[kc], kf0, s0, 0, 0, 0);
      const float* kp1 = kbase + (size_t)(kt + 16 + l15) * DD + kc * 32 + lg * 8;
      a = *(const float4*)kp1; bb = *(const float4*)(kp1 + 4);
      f16x8 kf1; kf1[0]=(_Float16)a.x;kf1[1]=(_Float16)a.y;kf1[2]=(_Float16)a.z;kf1[3]=(_Float16)a.w;
      kf1[4]=(_Float16)bb.x;kf1[5]=(_Float16)bb.y;kf1[6]=(_Float16)bb.z;kf1[7]=(_Float16)bb.w;
      s1 = __builtin_amdgcn_mfma_f32_16x16x32_f16(qf[kc], kf1, s1, 0, 0, 0);
    }
    const float a0 = (mvb[kt + l15] != 0) ? 0.f : -1e9f;
    const float a1 = (mvb[kt + 16 + l15] != 0) ? 0.f : -1e9f;
    float pmx[4];
#pragma unroll
    for (int r = 0; r < 4; ++r) {
      s0[r] = s0[r] * scale + a0; s1[r] = s1[r] * scale + a1;
      pmx[r] = fmaxf(s0[r], s1[r]);
    }
#pragma unroll
    for (int off = 1; off < 16; off <<= 1)
#pragma unroll
      for (int r = 0; r < 4; ++r) pmx[r] = fmaxf(pmx[r], __shfl_xor(pmx[r], off, 64));
    float al[4], ps[4];
#pragma unroll
    for (int r = 0; r < 4; ++r) {
      float mn = fmaxf(m[r], pmx[r]);
      al[r] = __expf(m[r] - mn); m[r] = mn;
      float p0 = __expf(s0[r] - mn), p1 = __expf(s1[r] - mn);
      ps[r] = p0 + p1;
      int row = lg * 4 + r;
      plds[row * 40 + l15] = (_Float16)p0;
      plds[row * 40 + 16 + l15] = (_Float16)p1;
    }
#pragma unroll
    for (int off = 1; off < 16; off <<= 1)
#pragma unroll
      for (int r = 0; r < 4; ++r) ps[r] += __shfl_xor(ps[r], off, 64);
#pragma unroll
    for (int r = 0; r < 4; ++r) {
      lsum[r] = lsum[r] * al[r] + ps[r];
#pragma unroll
      for (int ct = 0; ct < 8; ++ct) acc[ct][r] *= al[r];
    }
    f16x8 pa = *(const f16x8*)&plds[l15 * 40 + lg * 8];
#pragma unroll
    for (int ct = 0; ct < 8; ++ct) {
      const float* vp = vbase + (size_t)(kt + lg * 8) * DD + ct * 16 + l15;
      f16x8 vf;
#pragma unroll
      for (int j = 0; j < 8; ++j) vf[j] = (_Float16)vp[(size_t)j * DD];
      acc[ct] = __builtin_amdgcn_mfma_f32_16x16x32_f16(pa, vf, acc[ct], 0, 0, 0);
    }
  }
  const int* mqb = mask_q + b * TQ;
#pragma unroll
  for (int r = 0; r < 4; ++r) {
    int row = lg * 4 + r;
    int qr = qbase + row;
    float f = ((mqb[qr] != 0) ? 1.f : 0.f) / lsum[r];
    float* orow = out + ((size_t)b * TQ + qr) * DD;
#pragma unroll
    for (int ct = 0; ct < 8; ++ct) orow[ct * 16 + l15] = acc[ct][r] * f;
  }
}

extern "C" void kernel_launch(void* const* d_in, const int* in_sizes, int n_in,
                              void* d_out, int out_size, void* d_ws, size_t ws_size,
                              hipStream_t stream) {
  const float* q      = (const float*)d_in[0];
  const float* v      = (const float*)d_in[1];
  const float* k      = (const float*)d_in[2];
  const float* scale  = (const float*)d_in[3];
  const int*   mask_q = (const int*)d_in[4];
  const int*   mask_v = (const int*)d_in[5];
  float* out = (float*)d_out;

  const size_t need = 3ull * NB * TV * DD * sizeof(_Float16);  // 12 MB
  if (ws_size >= need) {
    _Float16* qh = (_Float16*)d_ws;
    _Float16* kh = qh + (size_t)NB * TQ * DD;
    _Float16* vt = kh + (size_t)NB * TV * DD;
    hipLaunchKernelGGL(prepass_kernel, dim3(4096 + 2048), dim3(256), 0, stream,
                       q, k, v, scale, qh, kh, vt);
    hipLaunchKernelGGL(attn_main, dim3(NB * (TQ / 32)), dim3(256), 0, stream,
                       qh, kh, vt, mask_q, mask_v, out);
  } else {
    hipLaunchKernelGGL(attn_f32_kernel, dim3(NB * (TQ / 16)), dim3(64), 0, stream,
                       q, v, k, scale, mask_q, mask_v, out);
  }
}

// Round 7
// 57.296 us; speedup vs baseline: 2.2633x; 1.4119x over previous
//
#include <hip/hip_runtime.h>
#include <cstddef>

#define NB 8
#define TQ 2048
#define TV 2048
#define DD 128
#define KVT 32
#define NWV 4           // waves per block; chunk = 512 KV rows/wave (PROVEN: FETCH ~6 MB)
#define CHW (TV / NWV)  // 512
#define NT  (CHW / KVT) // 16 tiles per wave

typedef _Float16 f16x8 __attribute__((ext_vector_type(8)));
typedef _Float16 f16x4 __attribute__((ext_vector_type(4)));
typedef float f32x4 __attribute__((ext_vector_type(4)));

// DPP row rotate (within 16-lane row)
template <int CTRL>
__device__ __forceinline__ float dpp_mov(float x) {
  return __builtin_bit_cast(float,
      __builtin_amdgcn_update_dpp(0, __builtin_bit_cast(int, x), CTRL, 0xF, 0xF, true));
}
__device__ __forceinline__ float rowmax16(float x) {
  x = fmaxf(x, dpp_mov<0x128>(x));  // row_ror:8
  x = fmaxf(x, dpp_mov<0x124>(x));  // row_ror:4
  x = fmaxf(x, dpp_mov<0x122>(x));  // row_ror:2
  x = fmaxf(x, dpp_mov<0x121>(x));  // row_ror:1
  return x;
}

// ------- prepass -----------------------------------------------------------
// qh  = scale * f16(q)                       [B][TQ][128]      (flat cast)
// kh2 = f16(k) tiled: [B][64 kt][4 kc][32 row][32 dk]   (fragment = 1KB contiguous)
// vt2 = f16(v)^T tiled: [B][64 kt][128 d][32 kv]        (fragment = 1KB contiguous)
__global__ __launch_bounds__(256) void prepass_kernel(
    const float* __restrict__ q, const float* __restrict__ k,
    const float* __restrict__ v, const float* __restrict__ scale_p,
    _Float16* __restrict__ qh, _Float16* __restrict__ kh2, _Float16* __restrict__ vt2)
{
  __shared__ _Float16 tlds[32 * 34];
  const int tid = threadIdx.x;
  const int bid = blockIdx.x;
  if (bid < 2048) {                       // cast+scale Q
    const float sc = scale_p[0];
    size_t idx = (size_t)bid * 256 + tid;
    float4 x = ((const float4*)q)[idx];
    f16x4 h; h[0] = (_Float16)(sc * x.x); h[1] = (_Float16)(sc * x.y);
    h[2] = (_Float16)(sc * x.z); h[3] = (_Float16)(sc * x.w);
    ((f16x4*)qh)[idx] = h;
  } else if (bid < 2048 + 512) {          // K tiles: one 32x128 tile per block
    int tb = bid - 2048;                  // b*64 + kt
    int b = tb >> 6, kt = tb & 63;
    int row = tid >> 3, d0 = (tid & 7) * 4;
    const float* src = k + ((size_t)(b * TV + kt * 32 + row)) * DD;
    _Float16* dst = kh2 + ((size_t)(b * 64 + kt)) * 4096;
#pragma unroll
    for (int it = 0; it < 4; ++it) {      // kc = it
      float4 x = *(const float4*)(src + it * 32 + d0);
      f16x4 h; h[0] = (_Float16)x.x; h[1] = (_Float16)x.y;
      h[2] = (_Float16)x.z; h[3] = (_Float16)x.w;
      *(f16x4*)(dst + it * 1024 + row * 32 + d0) = h;
    }
  } else {                                // V transpose tiles 32x32
    int tb = bid - 2048 - 512;            // 8 b * 64 kt * 4 dt
    int b = tb >> 8, rem = tb & 255;
    int kt = rem >> 2, dt = rem & 3;
    int r = tid >> 3, c0 = (tid & 7) * 4;
    float4 x = *(const float4*)&v[((size_t)b * TV + kt * 32 + r) * DD + dt * 32 + c0];
    tlds[(c0 + 0) * 34 + r] = (_Float16)x.x;
    tlds[(c0 + 1) * 34 + r] = (_Float16)x.y;
    tlds[(c0 + 2) * 34 + r] = (_Float16)x.z;
    tlds[(c0 + 3) * 34 + r] = (_Float16)x.w;
    __syncthreads();
    int dl = tid >> 3, k0 = (tid & 7) * 4;
    f16x4 h;
#pragma unroll
    for (int i = 0; i < 4; ++i) h[i] = tlds[dl * 34 + k0 + i];
    size_t eidx = (((size_t)b * 64 + kt) * 128 + (dt * 32 + dl)) * 32 + k0;
    *(f16x4*)&vt2[eidx] = h;
  }
}

// ------- main: grid 512 (b=blk&7), 4 waves x 32 Q rows x 512-KV chunk ----------
__global__ __launch_bounds__(256, 2) void attn_main(
    const _Float16* __restrict__ qh, const _Float16* __restrict__ kh2,
    const _Float16* __restrict__ vt2,
    const int* __restrict__ mask_q, const int* __restrict__ mask_v,
    float* __restrict__ out)
{
  __shared__ __align__(16) _Float16 plds_all[NWV][2][16 * 40];
  __shared__ __align__(16) float osh[32 * 132];
  __shared__ float msh[NWV][32], lsh[NWV][32];

  const int tid = threadIdx.x;
  const int w = tid >> 6;
  const int lane = tid & 63;
  const int l15 = lane & 15, lg = lane >> 4;

  const int b = blockIdx.x & 7;            // batch -> XCD affinity (proven mapping)
  const int qg = blockIdx.x >> 3;          // 0..63
  const int qbase = qg * 32;
  const int t0 = w * (NT);                 // first tile index of this wave's chunk... (see kt below)

  const _Float16* qhb = qh + ((size_t)b * TQ + qbase) * DD;
  const _Float16* ktiles = kh2 + (size_t)b * 64 * 4096;
  const _Float16* vtiles = vt2 + (size_t)b * 64 * 4096;
  const int* mvb = mask_v + b * TV;

  f16x8 qf[2][4];
#pragma unroll
  for (int rb = 0; rb < 2; ++rb)
#pragma unroll
    for (int kc = 0; kc < 4; ++kc)
      qf[rb][kc] = *(const f16x8*)(qhb + (size_t)(rb * 16 + l15) * DD + kc * 32 + lg * 8);

  f16x8 vones;
#pragma unroll
  for (int j = 0; j < 8; ++j) vones[j] = (_Float16)1.f;

  f32x4 acc[2][8];
  f32x4 accl[2];
#pragma unroll
  for (int rb = 0; rb < 2; ++rb) {
    accl[rb] = (f32x4){0.f, 0.f, 0.f, 0.f};
#pragma unroll
    for (int ct = 0; ct < 8; ++ct) acc[rb][ct] = (f32x4){0.f, 0.f, 0.f, 0.f};
  }
  float m[2][4];
#pragma unroll
  for (int rb = 0; rb < 2; ++rb)
#pragma unroll
    for (int r = 0; r < 4; ++r) m[rb][r] = -3.0e38f;

  for (int t = 0; t < NT; ++t) {
    const int tile = w * NT + t;               // tile index 0..63
    const int kt = tile * KVT;                 // KV row base (for mask)
    const _Float16* ktb = ktiles + (size_t)tile * 4096;
    const _Float16* vtb = vtiles + (size_t)tile * 4096;

    // ---- QK^T : K fragments are contiguous 1KB wave-loads ----
    f32x4 s[2][2];
    s[0][0] = (f32x4){0,0,0,0}; s[0][1] = (f32x4){0,0,0,0};
    s[1][0] = (f32x4){0,0,0,0}; s[1][1] = (f32x4){0,0,0,0};
    __builtin_amdgcn_s_setprio(1);
#pragma unroll
    for (int kc = 0; kc < 4; ++kc) {
      f16x8 kf0 = *(const f16x8*)(ktb + kc * 1024 + l15 * 32 + lg * 8);
      f16x8 kf1 = *(const f16x8*)(ktb + kc * 1024 + (16 + l15) * 32 + lg * 8);
      s[0][0] = __builtin_amdgcn_mfma_f32_16x16x32_f16(qf[0][kc], kf0, s[0][0], 0, 0, 0);
      s[1][0] = __builtin_amdgcn_mfma_f32_16x16x32_f16(qf[1][kc], kf0, s[1][0], 0, 0, 0);
      s[0][1] = __builtin_amdgcn_mfma_f32_16x16x32_f16(qf[0][kc], kf1, s[0][1], 0, 0, 0);
      s[1][1] = __builtin_amdgcn_mfma_f32_16x16x32_f16(qf[1][kc], kf1, s[1][1], 0, 0, 0);
    }
    __builtin_amdgcn_s_setprio(0);

    // ---- V fragments: contiguous 1KB wave-loads, issued early ----
    f16x8 vf[8];
#pragma unroll
    for (int ct = 0; ct < 8; ++ct)
      vf[ct] = *(const f16x8*)(vtb + (ct * 16 + l15) * 32 + lg * 8);

    const float a0 = (mvb[kt + l15]      != 0) ? 0.f : -1e9f;
    const float a1 = (mvb[kt + 16 + l15] != 0) ? 0.f : -1e9f;

    // ---- softmax (DPP row-max, defer-max, exp, LDS P-transpose) ----
    f16x8 pa[2];
#pragma unroll
    for (int rb = 0; rb < 2; ++rb) {
      float pmx[4];
      bool grow = false;
#pragma unroll
      for (int r = 0; r < 4; ++r) {
        s[rb][0][r] += a0;
        s[rb][1][r] += a1;
        pmx[r] = rowmax16(fmaxf(s[rb][0][r], s[rb][1][r]));
        grow = grow || (pmx[r] > m[rb][r] + 8.f);
      }
      if (__any(grow)) {
        f32x4 alv;
#pragma unroll
        for (int r = 0; r < 4; ++r) {
          float mn = fmaxf(m[rb][r], pmx[r]);
          alv[r] = __expf(m[rb][r] - mn);
          m[rb][r] = mn;
        }
        accl[rb] *= alv;
#pragma unroll
        for (int ct = 0; ct < 8; ++ct) acc[rb][ct] *= alv;
      }
      _Float16* pl = plds_all[w][rb];
#pragma unroll
      for (int r = 0; r < 4; ++r) {
        float p0 = __expf(s[rb][0][r] - m[rb][r]);
        float p1 = __expf(s[rb][1][r] - m[rb][r]);
        int row = lg * 4 + r;
        pl[row * 40 + l15]      = (_Float16)p0;
        pl[row * 40 + 16 + l15] = (_Float16)p1;
      }
      pa[rb] = *(const f16x8*)(pl + l15 * 40 + lg * 8);
    }

    // ---- PV (+ ones-column MFMA folds row-sum into accl) ----
    __builtin_amdgcn_s_setprio(1);
#pragma unroll
    for (int ct = 0; ct < 8; ++ct) {
      acc[0][ct] = __builtin_amdgcn_mfma_f32_16x16x32_f16(pa[0], vf[ct], acc[0][ct], 0, 0, 0);
      acc[1][ct] = __builtin_amdgcn_mfma_f32_16x16x32_f16(pa[1], vf[ct], acc[1][ct], 0, 0, 0);
    }
    accl[0] = __builtin_amdgcn_mfma_f32_16x16x32_f16(pa[0], vones, accl[0], 0, 0, 0);
    accl[1] = __builtin_amdgcn_mfma_f32_16x16x32_f16(pa[1], vones, accl[1], 0, 0, 0);
    __builtin_amdgcn_s_setprio(0);
  }

  // ---- publish per-wave stats ----
  if (l15 == 0) {
#pragma unroll
    for (int rb = 0; rb < 2; ++rb)
#pragma unroll
      for (int r = 0; r < 4; ++r) {
        msh[w][rb * 16 + lg * 4 + r] = m[rb][r];
        lsh[w][rb * 16 + lg * 4 + r] = accl[rb][r];
      }
  }
  __syncthreads();

  float coef[2][4];
#pragma unroll
  for (int rb = 0; rb < 2; ++rb)
#pragma unroll
    for (int r = 0; r < 4; ++r) {
      int row = rb * 16 + lg * 4 + r;
      float mstar = msh[0][row];
#pragma unroll
      for (int wv = 1; wv < NWV; ++wv) mstar = fmaxf(mstar, msh[wv][row]);
      coef[rb][r] = __expf(m[rb][r] - mstar);
    }

#pragma unroll
  for (int wv = 0; wv < NWV; ++wv) {
    if (w == wv) {
#pragma unroll
      for (int rb = 0; rb < 2; ++rb)
#pragma unroll
        for (int ct = 0; ct < 8; ++ct)
#pragma unroll
          for (int r = 0; r < 4; ++r) {
            int idx = (rb * 16 + lg * 4 + r) * 132 + ct * 16 + l15;
            float val = coef[rb][r] * acc[rb][ct][r];
            if (wv == 0) osh[idx] = val; else osh[idx] += val;
          }
    }
    __syncthreads();
  }

  // ---- final normalize + query-mask + store ----
  {
    const int row = tid >> 3;            // 0..31
    const int cg = (tid & 7) * 16;       // 0..112
    float mstar = msh[0][row];
#pragma unroll
    for (int wv = 1; wv < NWV; ++wv) mstar = fmaxf(mstar, msh[wv][row]);
    float lstar = 0.f;
#pragma unroll
    for (int wv = 0; wv < NWV; ++wv)
      lstar += __expf(msh[wv][row] - mstar) * lsh[wv][row];
    const int qr = qbase + row;
    const float f = ((mask_q[(size_t)b * TQ + qr] != 0) ? 1.f : 0.f) / lstar;
    float* orow = out + ((size_t)b * TQ + qr) * DD + cg;
#pragma unroll
    for (int i4 = 0; i4 < 4; ++i4) {
      float4 p = *(float4*)&osh[row * 132 + cg + i4 * 4];
      float4 o; o.x = p.x * f; o.y = p.y * f; o.z = p.z * f; o.w = p.w * f;
      *(float4*)(orow + i4 * 4) = o;
    }
  }
}

// ---------------- fallback (round-1 kernel) if ws too small --------------------
__global__ __launch_bounds__(64, 4) void attn_f32_kernel(
    const float* __restrict__ q, const float* __restrict__ v,
    const float* __restrict__ k, const float* __restrict__ scale_p,
    const int* __restrict__ mask_q, const int* __restrict__ mask_v,
    float* __restrict__ out)
{
  __shared__ __align__(16) _Float16 plds[16 * 40];
  const int lane = threadIdx.x & 63;
  const int l15 = lane & 15, lg = lane >> 4;
  const int qblocks = TQ / 16;
  const int b = blockIdx.x / qblocks, qb = blockIdx.x % qblocks;
  const int qbase = qb * 16;
  const float scale = scale_p[0];
  const float* qp = q + ((size_t)b * TQ + qbase) * DD;
  const float* kbase = k + (size_t)b * TV * DD;
  const float* vbase = v + (size_t)b * TV * DD;
  const int* mvb = mask_v + b * TV;
  f16x8 qf[4];
#pragma unroll
  for (int kc = 0; kc < 4; ++kc) {
    float4 a = *(const float4*)(qp + (size_t)l15 * DD + kc * 32 + lg * 8);
    float4 bb = *(const float4*)(qp + (size_t)l15 * DD + kc * 32 + lg * 8 + 4);
    f16x8 h; h[0]=(_Float16)a.x;h[1]=(_Float16)a.y;h[2]=(_Float16)a.z;h[3]=(_Float16)a.w;
    h[4]=(_Float16)bb.x;h[5]=(_Float16)bb.y;h[6]=(_Float16)bb.z;h[7]=(_Float16)bb.w;
    qf[kc]=h;
  }
  f32x4 acc[8];
#pragma unroll
  for (int i = 0; i < 8; ++i) acc[i] = (f32x4){0.f,0.f,0.f,0.f};
  float m[4], lsum[4];
#pragma unroll
  for (int r = 0; r < 4; ++r) { m[r] = -3.0e38f; lsum[r] = 0.f; }
  for (int kt = 0; kt < TV; kt += KVT) {
    f32x4 s0 = {0,0,0,0}, s1 = {0,0,0,0};
#pragma unroll
    for (int kc = 0; kc < 4; ++kc) {
      const float* kp0 = kbase + (size_t)(kt + l15) * DD + kc * 32 + lg * 8;
      float4 a = *(const float4*)kp0; float4 bb = *(const float4*)(kp0 + 4);
      f16x8 kf0; kf0[0]=(_Float16)a.x;kf0[1]=(_Float16)a.y;kf0[2]=(_Float16)a.z;kf0[3]=(_Float16)a.w;
      kf0[4]=(_Float16)bb.x;kf0[5]=(_Float16)bb.y;kf0[6]=(_Float16)bb.z;kf0[7]=(_Float16)bb.w;
      s0 = __builtin_amdgcn_mfma_f32_16x16x32_f16(qf[kc], kf0, s0, 0, 0, 0);
      const float* kp1 = kbase + (size_t)(kt + 16 + l15) * DD + kc * 32 + lg * 8;
      a = *(const float4*)kp1; bb = *(const float4*)(kp1 + 4);
      f16x8 kf1; kf1[0]=(_Float16)a.x;kf1[1]=(_Float16)a.y;kf1[2]=(_Float16)a.z;kf1[3]=(_Float16)a.w;
      kf1[4]=(_Float16)bb.x;kf1[5]=(_Float16)bb.y;kf1[6]=(_Float16)bb.z;kf1[7]=(_Float16)bb.w;
      s1 = __builtin_amdgcn_mfma_f32_16x16x32_f16(qf[kc], kf1, s1, 0, 0, 0);
    }
    const float a0 = (mvb[kt + l15] != 0) ? 0.f : -1e9f;
    const float a1 = (mvb[kt + 16 + l15] != 0) ? 0.f : -1e9f;
    float pmx[4];
#pragma unroll
    for (int r = 0; r < 4; ++r) {
      s0[r] = s0[r] * scale + a0; s1[r] = s1[r] * scale + a1;
      pmx[r] = fmaxf(s0[r], s1[r]);
    }
#pragma unroll
    for (int off = 1; off < 16; off <<= 1)
#pragma unroll
      for (int r = 0; r < 4; ++r) pmx[r] = fmaxf(pmx[r], __shfl_xor(pmx[r], off, 64));
    float al[4], ps[4];
#pragma unroll
    for (int r = 0; r < 4; ++r) {
      float mn = fmaxf(m[r], pmx[r]);
      al[r] = __expf(m[r] - mn); m[r] = mn;
      float p0 = __expf(s0[r] - mn), p1 = __expf(s1[r] - mn);
      ps[r] = p0 + p1;
      int row = lg * 4 + r;
      plds[row * 40 + l15] = (_Float16)p0;
      plds[row * 40 + 16 + l15] = (_Float16)p1;
    }
#pragma unroll
    for (int off = 1; off < 16; off <<= 1)
#pragma unroll
      for (int r = 0; r < 4; ++r) ps[r] += __shfl_xor(ps[r], off, 64);
#pragma unroll
    for (int r = 0; r < 4; ++r) {
      lsum[r] = lsum[r] * al[r] + ps[r];
#pragma unroll
      for (int ct = 0; ct < 8; ++ct) acc[ct][r] *= al[r];
    }
    f16x8 pa = *(const f16x8*)&plds[l15 * 40 + lg * 8];
#pragma unroll
    for (int ct = 0; ct < 8; ++ct) {
      const float* vp = vbase + (size_t)(kt + lg * 8) * DD + ct * 16 + l15;
      f16x8 vfx;
#pragma unroll
      for (int j = 0; j < 8; ++j) vfx[j] = (_Float16)vp[(size_t)j * DD];
      acc[ct] = __builtin_amdgcn_mfma_f32_16x16x32_f16(pa, vfx, acc[ct], 0, 0, 0);
    }
  }
  const int* mqb = mask_q + b * TQ;
#pragma unroll
  for (int r = 0; r < 4; ++r) {
    int row = lg * 4 + r;
    int qr = qbase + row;
    float f = ((mqb[qr] != 0) ? 1.f : 0.f) / lsum[r];
    float* orow = out + ((size_t)b * TQ + qr) * DD;
#pragma unroll
    for (int ct = 0; ct < 8; ++ct) orow[ct * 16 + l15] = acc[ct][r] * f;
  }
}

extern "C" void kernel_launch(void* const* d_in, const int* in_sizes, int n_in,
                              void* d_out, int out_size, void* d_ws, size_t ws_size,
                              hipStream_t stream) {
  const float* q      = (const float*)d_in[0];
  const float* v      = (const float*)d_in[1];
  const float* k      = (const float*)d_in[2];
  const float* scale  = (const float*)d_in[3];
  const int*   mask_q = (const int*)d_in[4];
  const int*   mask_v = (const int*)d_in[5];
  float* out = (float*)d_out;

  const size_t need = 3ull * NB * TV * DD * sizeof(_Float16);  // 12 MB
  if (ws_size >= need) {
    _Float16* qh  = (_Float16*)d_ws;
    _Float16* kh2 = qh + (size_t)NB * TQ * DD;
    _Float16* vt2 = kh2 + (size_t)NB * TV * DD;
    hipLaunchKernelGGL(prepass_kernel, dim3(2048 + 512 + 2048), dim3(256), 0, stream,
                       q, k, v, scale, qh, kh2, vt2);
    hipLaunchKernelGGL(attn_main, dim3(NB * (TQ / 32)), dim3(256), 0, stream,
                       qh, kh2, vt2, mask_q, mask_v, out);
  } else {
    hipLaunchKernelGGL(attn_f32_kernel, dim3(NB * (TQ / 16)), dim3(64), 0, stream,
                       q, v, k, scale, mask_q, mask_v, out);
  }
}

// Round 8
// 56.547 us; speedup vs baseline: 2.2933x; 1.0132x over previous
//
#include <hip/hip_runtime.h>
#include <cstddef>

#define NB 8
#define TQ 2048
#define TV 2048
#define DD 128
#define KVT 32
#define NWV 4           // waves per block; chunk = 512 KV rows/wave (PROVEN shape)
#define CHW (TV / NWV)  // 512
#define NT  (CHW / KVT) // 16 tiles per wave

typedef _Float16 f16x8 __attribute__((ext_vector_type(8)));
typedef _Float16 f16x4 __attribute__((ext_vector_type(4)));
typedef float f32x4 __attribute__((ext_vector_type(4)));

// DPP row rotate (within 16-lane row)
template <int CTRL>
__device__ __forceinline__ float dpp_mov(float x) {
  return __builtin_bit_cast(float,
      __builtin_amdgcn_update_dpp(0, __builtin_bit_cast(int, x), CTRL, 0xF, 0xF, true));
}
__device__ __forceinline__ float rowmax16(float x) {
  x = fmaxf(x, dpp_mov<0x128>(x));  // row_ror:8
  x = fmaxf(x, dpp_mov<0x124>(x));  // row_ror:4
  x = fmaxf(x, dpp_mov<0x122>(x));  // row_ror:2
  x = fmaxf(x, dpp_mov<0x121>(x));  // row_ror:1
  return x;
}

// ------- prepass -----------------------------------------------------------
// qh  = scale * f16(q)                       [B][TQ][128]
// kh2 = f16(k) tiled: [B][64 kt][4 kc][32 row][32 dk]   (fragment = 1KB contiguous)
// vt2 = f16(v)^T tiled: [B][64 kt][128 d][32 kv]        (fragment = 1KB contiguous)
__global__ __launch_bounds__(256) void prepass_kernel(
    const float* __restrict__ q, const float* __restrict__ k,
    const float* __restrict__ v, const float* __restrict__ scale_p,
    _Float16* __restrict__ qh, _Float16* __restrict__ kh2, _Float16* __restrict__ vt2)
{
  __shared__ _Float16 tlds[32 * 34];
  const int tid = threadIdx.x;
  const int bid = blockIdx.x;
  if (bid < 2048) {                       // cast+scale Q
    const float sc = scale_p[0];
    size_t idx = (size_t)bid * 256 + tid;
    float4 x = ((const float4*)q)[idx];
    f16x4 h; h[0] = (_Float16)(sc * x.x); h[1] = (_Float16)(sc * x.y);
    h[2] = (_Float16)(sc * x.z); h[3] = (_Float16)(sc * x.w);
    ((f16x4*)qh)[idx] = h;
  } else if (bid < 2048 + 512) {          // K tiles: one 32x128 tile per block
    int tb = bid - 2048;                  // b*64 + kt
    int b = tb >> 6, kt = tb & 63;
    int row = tid >> 3, d0 = (tid & 7) * 4;
    const float* src = k + ((size_t)(b * TV + kt * 32 + row)) * DD;
    _Float16* dst = kh2 + ((size_t)(b * 64 + kt)) * 4096;
#pragma unroll
    for (int it = 0; it < 4; ++it) {      // kc = it
      float4 x = *(const float4*)(src + it * 32 + d0);
      f16x4 h; h[0] = (_Float16)x.x; h[1] = (_Float16)x.y;
      h[2] = (_Float16)x.z; h[3] = (_Float16)x.w;
      *(f16x4*)(dst + it * 1024 + row * 32 + d0) = h;
    }
  } else {                                // V transpose tiles 32x32
    int tb = bid - 2048 - 512;            // 8 b * 64 kt * 4 dt
    int b = tb >> 8, rem = tb & 255;
    int kt = rem >> 2, dt = rem & 3;
    int r = tid >> 3, c0 = (tid & 7) * 4;
    float4 x = *(const float4*)&v[((size_t)b * TV + kt * 32 + r) * DD + dt * 32 + c0];
    tlds[(c0 + 0) * 34 + r] = (_Float16)x.x;
    tlds[(c0 + 1) * 34 + r] = (_Float16)x.y;
    tlds[(c0 + 2) * 34 + r] = (_Float16)x.z;
    tlds[(c0 + 3) * 34 + r] = (_Float16)x.w;
    __syncthreads();
    int dl = tid >> 3, k0 = (tid & 7) * 4;
    f16x4 h;
#pragma unroll
    for (int i = 0; i < 4; ++i) h[i] = tlds[dl * 34 + k0 + i];
    size_t eidx = (((size_t)b * 64 + kt) * 128 + (dt * 32 + dl)) * 32 + k0;
    *(f16x4*)&vt2[eidx] = h;
  }
}

// ------- main: grid 512 (b=blk&7), 4 waves x 32 Q rows x 512-KV chunk ----------
// K register double-buffer (cross-tile prefetch); V issued at top of each step.
__global__ __launch_bounds__(256, 2) void attn_main(
    const _Float16* __restrict__ qh, const _Float16* __restrict__ kh2,
    const _Float16* __restrict__ vt2,
    const int* __restrict__ mask_q, const int* __restrict__ mask_v,
    float* __restrict__ out)
{
  __shared__ __align__(16) _Float16 plds_all[NWV][2][16 * 40];
  __shared__ __align__(16) float osh[32 * 132];
  __shared__ float msh[NWV][32], lsh[NWV][32];

  const int tid = threadIdx.x;
  const int w = tid >> 6;
  const int lane = tid & 63;
  const int l15 = lane & 15, lg = lane >> 4;

  const int b = blockIdx.x & 7;            // batch -> XCD affinity (proven mapping)
  const int qg = blockIdx.x >> 3;          // 0..63
  const int qbase = qg * 32;

  const _Float16* qhb = qh + ((size_t)b * TQ + qbase) * DD;
  const _Float16* ktiles = kh2 + (size_t)b * 64 * 4096;
  const _Float16* vtiles = vt2 + (size_t)b * 64 * 4096;
  const int* mvb = mask_v + b * TV;

  f16x8 qf[2][4];
#pragma unroll
  for (int rb = 0; rb < 2; ++rb)
#pragma unroll
    for (int kc = 0; kc < 4; ++kc)
      qf[rb][kc] = *(const f16x8*)(qhb + (size_t)(rb * 16 + l15) * DD + kc * 32 + lg * 8);

  f16x8 vones;
#pragma unroll
  for (int j = 0; j < 8; ++j) vones[j] = (_Float16)1.f;

  f32x4 acc[2][8];
  f32x4 accl[2];
#pragma unroll
  for (int rb = 0; rb < 2; ++rb) {
    accl[rb] = (f32x4){0.f, 0.f, 0.f, 0.f};
#pragma unroll
    for (int ct = 0; ct < 8; ++ct) acc[rb][ct] = (f32x4){0.f, 0.f, 0.f, 0.f};
  }
  float m[2][4];
#pragma unroll
  for (int rb = 0; rb < 2; ++rb)
#pragma unroll
    for (int r = 0; r < 4; ++r) m[rb][r] = -3.0e38f;

  const int tbase = w * NT;

  f16x8 ka[8], kb[8];

  // prologue: K(tile 0) -> ka
  {
    const _Float16* kt0 = ktiles + (size_t)tbase * 4096;
#pragma unroll
    for (int kc = 0; kc < 4; ++kc) {
      ka[2 * kc]     = *(const f16x8*)(kt0 + kc * 1024 + l15 * 32 + lg * 8);
      ka[2 * kc + 1] = *(const f16x8*)(kt0 + kc * 1024 + (16 + l15) * 32 + lg * 8);
    }
  }

  // one pipeline step: prefetch K(tilep)->kpre, load V(tile), compute tile from kcur
  auto step = [&](int tile, f16x8 (&kcur)[8], f16x8 (&kpre)[8], int tilep) {
    // 1) K prefetch for the NEXT tile (consumed first next step -> full-step lead)
    const _Float16* ktbp = ktiles + (size_t)tilep * 4096;
#pragma unroll
    for (int kc = 0; kc < 4; ++kc) {
      kpre[2 * kc]     = *(const f16x8*)(ktbp + kc * 1024 + l15 * 32 + lg * 8);
      kpre[2 * kc + 1] = *(const f16x8*)(ktbp + kc * 1024 + (16 + l15) * 32 + lg * 8);
    }
    // 2) V for THIS tile (consumed last in this step -> intra-step lead)
    const _Float16* vtb = vtiles + (size_t)tile * 4096;
    f16x8 vfr[8];
#pragma unroll
    for (int ct = 0; ct < 8; ++ct)
      vfr[ct] = *(const f16x8*)(vtb + (ct * 16 + l15) * 32 + lg * 8);
    // 3) mask for this tile
    const int kt = tile * KVT;
    const float a0 = (mvb[kt + l15]      != 0) ? 0.f : -1e9f;
    const float a1 = (mvb[kt + 16 + l15] != 0) ? 0.f : -1e9f;

    // 4) QK^T on kcur (registers already resident)
    f32x4 s[2][2];
    s[0][0] = (f32x4){0,0,0,0}; s[0][1] = (f32x4){0,0,0,0};
    s[1][0] = (f32x4){0,0,0,0}; s[1][1] = (f32x4){0,0,0,0};
    __builtin_amdgcn_s_setprio(1);
#pragma unroll
    for (int kc = 0; kc < 4; ++kc) {
      s[0][0] = __builtin_amdgcn_mfma_f32_16x16x32_f16(qf[0][kc], kcur[2*kc],   s[0][0], 0, 0, 0);
      s[1][0] = __builtin_amdgcn_mfma_f32_16x16x32_f16(qf[1][kc], kcur[2*kc],   s[1][0], 0, 0, 0);
      s[0][1] = __builtin_amdgcn_mfma_f32_16x16x32_f16(qf[0][kc], kcur[2*kc+1], s[0][1], 0, 0, 0);
      s[1][1] = __builtin_amdgcn_mfma_f32_16x16x32_f16(qf[1][kc], kcur[2*kc+1], s[1][1], 0, 0, 0);
    }
    __builtin_amdgcn_s_setprio(0);

    // 5) softmax (DPP row-max, defer-max, exp, LDS P-transpose)
    f16x8 pa[2];
#pragma unroll
    for (int rb = 0; rb < 2; ++rb) {
      float pmx[4];
      bool grow = false;
#pragma unroll
      for (int r = 0; r < 4; ++r) {
        s[rb][0][r] += a0;
        s[rb][1][r] += a1;
        pmx[r] = rowmax16(fmaxf(s[rb][0][r], s[rb][1][r]));
        grow = grow || (pmx[r] > m[rb][r] + 8.f);
      }
      if (__any(grow)) {
        f32x4 alv;
#pragma unroll
        for (int r = 0; r < 4; ++r) {
          float mn = fmaxf(m[rb][r], pmx[r]);
          alv[r] = __expf(m[rb][r] - mn);
          m[rb][r] = mn;
        }
        accl[rb] *= alv;
#pragma unroll
        for (int ct = 0; ct < 8; ++ct) acc[rb][ct] *= alv;
      }
      _Float16* pl = plds_all[w][rb];
#pragma unroll
      for (int r = 0; r < 4; ++r) {
        float p0 = __expf(s[rb][0][r] - m[rb][r]);
        float p1 = __expf(s[rb][1][r] - m[rb][r]);
        int row = lg * 4 + r;
        pl[row * 40 + l15]      = (_Float16)p0;
        pl[row * 40 + 16 + l15] = (_Float16)p1;
      }
      pa[rb] = *(const f16x8*)(pl + l15 * 40 + lg * 8);
    }

    // 6) PV + ones-column row-sum (V regs have had the whole step to arrive)
    __builtin_amdgcn_s_setprio(1);
#pragma unroll
    for (int ct = 0; ct < 8; ++ct) {
      acc[0][ct] = __builtin_amdgcn_mfma_f32_16x16x32_f16(pa[0], vfr[ct], acc[0][ct], 0, 0, 0);
      acc[1][ct] = __builtin_amdgcn_mfma_f32_16x16x32_f16(pa[1], vfr[ct], acc[1][ct], 0, 0, 0);
    }
    accl[0] = __builtin_amdgcn_mfma_f32_16x16x32_f16(pa[0], vones, accl[0], 0, 0, 0);
    accl[1] = __builtin_amdgcn_mfma_f32_16x16x32_f16(pa[1], vones, accl[1], 0, 0, 0);
    __builtin_amdgcn_s_setprio(0);
  };

#pragma unroll 1
  for (int t2 = 0; t2 < NT; t2 += 2) {
    step(tbase + t2,     ka, kb, tbase + t2 + 1);
    step(tbase + t2 + 1, kb, ka, (t2 + 2 < NT) ? (tbase + t2 + 2) : (tbase + t2 + 1));
  }

  // ---- publish per-wave stats ----
  if (l15 == 0) {
#pragma unroll
    for (int rb = 0; rb < 2; ++rb)
#pragma unroll
      for (int r = 0; r < 4; ++r) {
        msh[w][rb * 16 + lg * 4 + r] = m[rb][r];
        lsh[w][rb * 16 + lg * 4 + r] = accl[rb][r];
      }
  }
  __syncthreads();

  float coef[2][4];
#pragma unroll
  for (int rb = 0; rb < 2; ++rb)
#pragma unroll
    for (int r = 0; r < 4; ++r) {
      int row = rb * 16 + lg * 4 + r;
      float mstar = msh[0][row];
#pragma unroll
      for (int wv = 1; wv < NWV; ++wv) mstar = fmaxf(mstar, msh[wv][row]);
      coef[rb][r] = __expf(m[rb][r] - mstar);
    }

#pragma unroll
  for (int wv = 0; wv < NWV; ++wv) {
    if (w == wv) {
#pragma unroll
      for (int rb = 0; rb < 2; ++rb)
#pragma unroll
        for (int ct = 0; ct < 8; ++ct)
#pragma unroll
          for (int r = 0; r < 4; ++r) {
            int idx = (rb * 16 + lg * 4 + r) * 132 + ct * 16 + l15;
            float val = coef[rb][r] * acc[rb][ct][r];
            if (wv == 0) osh[idx] = val; else osh[idx] += val;
          }
    }
    __syncthreads();
  }

  // ---- final normalize + query-mask + store ----
  {
    const int row = tid >> 3;            // 0..31
    const int cg = (tid & 7) * 16;       // 0..112
    float mstar = msh[0][row];
#pragma unroll
    for (int wv = 1; wv < NWV; ++wv) mstar = fmaxf(mstar, msh[wv][row]);
    float lstar = 0.f;
#pragma unroll
    for (int wv = 0; wv < NWV; ++wv)
      lstar += __expf(msh[wv][row] - mstar) * lsh[wv][row];
    const int qr = qbase + row;
    const float f = ((mask_q[(size_t)b * TQ + qr] != 0) ? 1.f : 0.f) / lstar;
    float* orow = out + ((size_t)b * TQ + qr) * DD + cg;
#pragma unroll
    for (int i4 = 0; i4 < 4; ++i4) {
      float4 p = *(float4*)&osh[row * 132 + cg + i4 * 4];
      float4 o; o.x = p.x * f; o.y = p.y * f; o.z = p.z * f; o.w = p.w * f;
      *(float4*)(orow + i4 * 4) = o;
    }
  }
}

// ---------------- fallback (round-1 kernel) if ws too small --------------------
__global__ __launch_bounds__(64, 4) void attn_f32_kernel(
    const float* __restrict__ q, const float* __restrict__ v,
    const float* __restrict__ k, const float* __restrict__ scale_p,
    const int* __restrict__ mask_q, const int* __restrict__ mask_v,
    float* __restrict__ out)
{
  __shared__ __align__(16) _Float16 plds[16 * 40];
  const int lane = threadIdx.x & 63;
  const int l15 = lane & 15, lg = lane >> 4;
  const int qblocks = TQ / 16;
  const int b = blockIdx.x / qblocks, qb = blockIdx.x % qblocks;
  const int qbase = qb * 16;
  const float scale = scale_p[0];
  const float* qp = q + ((size_t)b * TQ + qbase) * DD;
  const float* kbase = k + (size_t)b * TV * DD;
  const float* vbase = v + (size_t)b * TV * DD;
  const int* mvb = mask_v + b * TV;
  f16x8 qf[4];
#pragma unroll
  for (int kc = 0; kc < 4; ++kc) {
    float4 a = *(const float4*)(qp + (size_t)l15 * DD + kc * 32 + lg * 8);
    float4 bb = *(const float4*)(qp + (size_t)l15 * DD + kc * 32 + lg * 8 + 4);
    f16x8 h; h[0]=(_Float16)a.x;h[1]=(_Float16)a.y;h[2]=(_Float16)a.z;h[3]=(_Float16)a.w;
    h[4]=(_Float16)bb.x;h[5]=(_Float16)bb.y;h[6]=(_Float16)bb.z;h[7]=(_Float16)bb.w;
    qf[kc]=h;
  }
  f32x4 acc[8];
#pragma unroll
  for (int i = 0; i < 8; ++i) acc[i] = (f32x4){0.f,0.f,0.f,0.f};
  float m[4], lsum[4];
#pragma unroll
  for (int r = 0; r < 4; ++r) { m[r] = -3.0e38f; lsum[r] = 0.f; }
  for (int kt = 0; kt < TV; kt += KVT) {
    f32x4 s0 = {0,0,0,0}, s1 = {0,0,0,0};
#pragma unroll
    for (int kc = 0; kc < 4; ++kc) {
      const float* kp0 = kbase + (size_t)(kt + l15) * DD + kc * 32 + lg * 8;
      float4 a = *(const float4*)kp0; float4 bb = *(const float4*)(kp0 + 4);
      f16x8 kf0; kf0[0]=(_Float16)a.x;kf0[1]=(_Float16)a.y;kf0[2]=(_Float16)a.z;kf0[3]=(_Float16)a.w;
      kf0[4]=(_Float16)bb.x;kf0[5]=(_Float16)bb.y;kf0[6]=(_Float16)bb.z;kf0[7]=(_Float16)bb.w;
      s0 = __builtin_amdgcn_mfma_f32_16x16x32_f16(qf[kc], kf0, s0, 0, 0, 0);
      const float* kp1 = kbase + (size_t)(kt + 16 + l15) * DD + kc * 32 + lg * 8;
      a = *(const float4*)kp1; bb = *(const float4*)(kp1 + 4);
      f16x8 kf1; kf1[0]=(_Float16)a.x;kf1[1]=(_Float16)a.y;kf1[2]=(_Float16)a.z;kf1[3]=(_Float16)a.w;
      kf1[4]=(_Float16)bb.x;kf1[5]=(_Float16)bb.y;kf1[6]=(_Float16)bb.z;kf1[7]=(_Float16)bb.w;
      s1 = __builtin_amdgcn_mfma_f32_16x16x32_f16(qf[kc], kf1, s1, 0, 0, 0);
    }
    const float a0 = (mvb[kt + l15] != 0) ? 0.f : -1e9f;
    const float a1 = (mvb[kt + 16 + l15] != 0) ? 0.f : -1e9f;
    float pmx[4];
#pragma unroll
    for (int r = 0; r < 4; ++r) {
      s0[r] = s0[r] * scale + a0; s1[r] = s1[r] * scale + a1;
      pmx[r] = fmaxf(s0[r], s1[r]);
    }
#pragma unroll
    for (int off = 1; off < 16; off <<= 1)
#pragma unroll
      for (int r = 0; r < 4; ++r) pmx[r] = fmaxf(pmx[r], __shfl_xor(pmx[r], off, 64));
    float al[4], ps[4];
#pragma unroll
    for (int r = 0; r < 4; ++r) {
      float mn = fmaxf(m[r], pmx[r]);
      al[r] = __expf(m[r] - mn); m[r] = mn;
      float p0 = __expf(s0[r] - mn), p1 = __expf(s1[r] - mn);
      ps[r] = p0 + p1;
      int row = lg * 4 + r;
      plds[row * 40 + l15] = (_Float16)p0;
      plds[row * 40 + 16 + l15] = (_Float16)p1;
    }
#pragma unroll
    for (int off = 1; off < 16; off <<= 1)
#pragma unroll
      for (int r = 0; r < 4; ++r) ps[r] += __shfl_xor(ps[r], off, 64);
#pragma unroll
    for (int r = 0; r < 4; ++r) {
      lsum[r] = lsum[r] * al[r] + ps[r];
#pragma unroll
      for (int ct = 0; ct < 8; ++ct) acc[ct][r] *= al[r];
    }
    f16x8 pa = *(const f16x8*)&plds[l15 * 40 + lg * 8];
#pragma unroll
    for (int ct = 0; ct < 8; ++ct) {
      const float* vp = vbase + (size_t)(kt + lg * 8) * DD + ct * 16 + l15;
      f16x8 vfx;
#pragma unroll
      for (int j = 0; j < 8; ++j) vfx[j] = (_Float16)vp[(size_t)j * DD];
      acc[ct] = __builtin_amdgcn_mfma_f32_16x16x32_f16(pa, vfx, acc[ct], 0, 0, 0);
    }
  }
  const int* mqb = mask_q + b * TQ;
#pragma unroll
  for (int r = 0; r < 4; ++r) {
    int row = lg * 4 + r;
    int qr = qbase + row;
    float f = ((mqb[qr] != 0) ? 1.f : 0.f) / lsum[r];
    float* orow = out + ((size_t)b * TQ + qr) * DD;
#pragma unroll
    for (int ct = 0; ct < 8; ++ct) orow[ct * 16 + l15] = acc[ct][r] * f;
  }
}

extern "C" void kernel_launch(void* const* d_in, const int* in_sizes, int n_in,
                              void* d_out, int out_size, void* d_ws, size_t ws_size,
                              hipStream_t stream) {
  const float* q      = (const float*)d_in[0];
  const float* v      = (const float*)d_in[1];
  const float* k      = (const float*)d_in[2];
  const float* scale  = (const float*)d_in[3];
  const int*   mask_q = (const int*)d_in[4];
  const int*   mask_v = (const int*)d_in[5];
  float* out = (float*)d_out;

  const size_t need = 3ull * NB * TV * DD * sizeof(_Float16);  // 12 MB
  if (ws_size >= need) {
    _Float16* qh  = (_Float16*)d_ws;
    _Float16* kh2 = qh + (size_t)NB * TQ * DD;
    _Float16* vt2 = kh2 + (size_t)NB * TV * DD;
    hipLaunchKernelGGL(prepass_kernel, dim3(2048 + 512 + 2048), dim3(256), 0, stream,
                       q, k, v, scale, qh, kh2, vt2);
    hipLaunchKernelGGL(attn_main, dim3(NB * (TQ / 32)), dim3(256), 0, stream,
                       qh, kh2, vt2, mask_q, mask_v, out);
  } else {
    hipLaunchKernelGGL(attn_f32_kernel, dim3(NB * (TQ / 16)), dim3(64), 0, stream,
                       q, v, k, scale, mask_q, mask_v, out);
  }
}